// Round 1
// baseline (2670.716 us; speedup 1.0000x reference)
//
#include <hip/hip_runtime.h>
#include <math.h>

#define BATCH 64
#define L 1024
#define DIM 640
#define INNER 256
#define OUTER 1024

// ---------------------------------------------------------------------------
// Kernel 1: projection GEMM  Y[M,256] = X[M,640] @ W[640,256] + bias
// M = 65536 (B*L). Tile BM=128 BN=64 BK=16, 256 threads, 8x4 per thread.
// ---------------------------------------------------------------------------
__global__ __launch_bounds__(256)
void proj_kernel(const float* __restrict__ X, const float* __restrict__ W,
                 const float* __restrict__ bias, float* __restrict__ Y)
{
    __shared__ float As[16][128];   // X^T tile (k-major)
    __shared__ float Bs[16][64];    // W tile   (k-major)
    const int tid = threadIdx.x;
    const int tx = tid & 15;        // -> N (4 cols)
    const int ty = tid >> 4;        // -> M (8 rows)
    const int bm = blockIdx.x * 128;
    const int bn = blockIdx.y * 64;

    const int arow = tid >> 1;          // 0..127
    const int acol = (tid & 1) * 8;     // 0,8
    const int bkr  = tid >> 4;          // 0..15
    const int bcol = (tid & 15) * 4;    // 0..60

    float acc[8][4];
    #pragma unroll
    for (int i = 0; i < 8; ++i)
        #pragma unroll
        for (int j = 0; j < 4; ++j) acc[i][j] = 0.f;

    const float* Xrow = X + (size_t)(bm + arow) * DIM;

    for (int k0 = 0; k0 < DIM; k0 += 16) {
        float4 xv0 = *(const float4*)(Xrow + k0 + acol);
        float4 xv1 = *(const float4*)(Xrow + k0 + acol + 4);
        float4 wv  = *(const float4*)(W + (size_t)(k0 + bkr) * INNER + bn + bcol);
        __syncthreads();
        As[acol+0][arow] = xv0.x; As[acol+1][arow] = xv0.y;
        As[acol+2][arow] = xv0.z; As[acol+3][arow] = xv0.w;
        As[acol+4][arow] = xv1.x; As[acol+5][arow] = xv1.y;
        As[acol+6][arow] = xv1.z; As[acol+7][arow] = xv1.w;
        *(float4*)&Bs[bkr][bcol] = wv;
        __syncthreads();
        #pragma unroll
        for (int kk = 0; kk < 16; ++kk) {
            float4 a0 = *(const float4*)&As[kk][ty*8];
            float4 a1 = *(const float4*)&As[kk][ty*8+4];
            float4 b0 = *(const float4*)&Bs[kk][tx*4];
            float av[8] = {a0.x,a0.y,a0.z,a0.w,a1.x,a1.y,a1.z,a1.w};
            float bw[4] = {b0.x,b0.y,b0.z,b0.w};
            #pragma unroll
            for (int i = 0; i < 8; ++i)
                #pragma unroll
                for (int j = 0; j < 4; ++j)
                    acc[i][j] = fmaf(av[i], bw[j], acc[i][j]);
        }
    }
    float4 bi = *(const float4*)(bias + bn + tx*4);
    #pragma unroll
    for (int i = 0; i < 8; ++i) {
        float4 o;
        o.x = acc[i][0] + bi.x; o.y = acc[i][1] + bi.y;
        o.z = acc[i][2] + bi.z; o.w = acc[i][3] + bi.w;
        *(float4*)(Y + (size_t)(bm + ty*8 + i) * INNER + bn + tx*4) = o;
    }
}

// ---------------------------------------------------------------------------
// Kernel 2a: per-batch scores S = Q @ K^T * scale, masked exp, store E,
// accumulate row sums l (atomic across k-tile blocks).
// Q,K: [BATCH][L][INNER] absolute; E: [group][L][L]; lsum: [BATCH][L]
// ---------------------------------------------------------------------------
__global__ __launch_bounds__(256)
void scores_kernel(const float* __restrict__ Q, const float* __restrict__ Km,
                   const int* __restrict__ len_k, float* __restrict__ E,
                   float* __restrict__ lsum, int b0)
{
    __shared__ float As[16][128];   // Q^T tile
    __shared__ float Bs[16][64];    // K^T tile (i-major)
    const int tid = threadIdx.x;
    const int tx = tid & 15;
    const int ty = tid >> 4;
    const int bz = blockIdx.z;          // group-local batch
    const int b  = b0 + bz;             // absolute batch
    const int bm = blockIdx.x * 128;    // q offset
    const int bn = blockIdx.y * 64;     // k offset

    const int arow = tid >> 1;
    const int acol = (tid & 1) * 8;
    const int krow = tid >> 2;          // 0..63
    const int kcol = (tid & 3) * 4;     // 0,4,8,12

    const float* Qb = Q  + ((size_t)b * L + bm) * INNER;
    const float* Kb = Km + ((size_t)b * L + bn) * INNER;

    float acc[8][4];
    #pragma unroll
    for (int i = 0; i < 8; ++i)
        #pragma unroll
        for (int j = 0; j < 4; ++j) acc[i][j] = 0.f;

    for (int k0 = 0; k0 < INNER; k0 += 16) {
        float4 qv0 = *(const float4*)(Qb + (size_t)arow * INNER + k0 + acol);
        float4 qv1 = *(const float4*)(Qb + (size_t)arow * INNER + k0 + acol + 4);
        float4 kv  = *(const float4*)(Kb + (size_t)krow * INNER + k0 + kcol);
        __syncthreads();
        As[acol+0][arow] = qv0.x; As[acol+1][arow] = qv0.y;
        As[acol+2][arow] = qv0.z; As[acol+3][arow] = qv0.w;
        As[acol+4][arow] = qv1.x; As[acol+5][arow] = qv1.y;
        As[acol+6][arow] = qv1.z; As[acol+7][arow] = qv1.w;
        Bs[kcol+0][krow] = kv.x; Bs[kcol+1][krow] = kv.y;
        Bs[kcol+2][krow] = kv.z; Bs[kcol+3][krow] = kv.w;
        __syncthreads();
        #pragma unroll
        for (int kk = 0; kk < 16; ++kk) {
            float4 a0 = *(const float4*)&As[kk][ty*8];
            float4 a1 = *(const float4*)&As[kk][ty*8+4];
            float4 b4 = *(const float4*)&Bs[kk][tx*4];
            float av[8] = {a0.x,a0.y,a0.z,a0.w,a1.x,a1.y,a1.z,a1.w};
            float bw[4] = {b4.x,b4.y,b4.z,b4.w};
            #pragma unroll
            for (int i = 0; i < 8; ++i)
                #pragma unroll
                for (int j = 0; j < 4; ++j)
                    acc[i][j] = fmaf(av[i], bw[j], acc[i][j]);
        }
    }

    const int lenk = len_k[b];
    const float scale = 0.0625f;   // 1/sqrt(256)
    const int kbase = bn + tx*4;
    float rs[8];
    #pragma unroll
    for (int i = 0; i < 8; ++i) {
        const int q = bm + ty*8 + i;
        float e0 = (kbase+0 < lenk) ? expf(acc[i][0]*scale) : 0.f;
        float e1 = (kbase+1 < lenk) ? expf(acc[i][1]*scale) : 0.f;
        float e2 = (kbase+2 < lenk) ? expf(acc[i][2]*scale) : 0.f;
        float e3 = (kbase+3 < lenk) ? expf(acc[i][3]*scale) : 0.f;
        rs[i] = (e0+e1)+(e2+e3);
        float4 ev = make_float4(e0,e1,e2,e3);
        *(float4*)(E + ((size_t)bz * L + q) * L + kbase) = ev;
    }
    __syncthreads();
    float* red = &As[0][0];        // reuse 8 KB LDS as [128][16]
    #pragma unroll
    for (int i = 0; i < 8; ++i) red[(ty*8+i)*16 + tx] = rs[i];
    __syncthreads();
    if (tid < 128) {
        float s = 0.f;
        #pragma unroll
        for (int t = 0; t < 16; ++t) s += red[tid*16 + t];
        atomicAdd(&lsum[(size_t)b * L + bm + tid], s);
    }
}

// ---------------------------------------------------------------------------
// Kernel 2b: w[b][k] = (1/len_q) * sum_{q<len_q} E[q][k] / l[q]
// ---------------------------------------------------------------------------
__global__ __launch_bounds__(256)
void colsum_kernel(const float* __restrict__ E, const float* __restrict__ lsum,
                   const int* __restrict__ len_q, float* __restrict__ w, int b0)
{
    const int bz = blockIdx.y;
    const int b  = b0 + bz;
    const int k  = blockIdx.x * 256 + threadIdx.x;
    const int lq = len_q[b];
    const float* Eb = E + (size_t)bz * L * L + k;
    const float* lb = lsum + (size_t)b * L;
    float a0=0.f, a1=0.f, a2=0.f, a3=0.f;
    int q = 0;
    for (; q + 4 <= lq; q += 4) {
        a0 += Eb[(size_t)(q+0)*L] * (1.0f/lb[q+0]);
        a1 += Eb[(size_t)(q+1)*L] * (1.0f/lb[q+1]);
        a2 += Eb[(size_t)(q+2)*L] * (1.0f/lb[q+2]);
        a3 += Eb[(size_t)(q+3)*L] * (1.0f/lb[q+3]);
    }
    for (; q < lq; ++q) a0 += Eb[(size_t)q*L] * (1.0f/lb[q]);
    w[(size_t)b * L + k] = (((a0+a1)+(a2+a3))) / (float)lq;
}

// ---------------------------------------------------------------------------
// Kernel 3: pooled[b][d] = sum_k w[b][k] * X[b][k][d]   (atomic over k-chunks)
// ---------------------------------------------------------------------------
__global__ __launch_bounds__(256)
void pool_kernel(const float* __restrict__ w, const float* __restrict__ X,
                 float* __restrict__ pooled)
{
    const int b   = blockIdx.y;
    const int kc  = blockIdx.x * 128;
    const int tid = threadIdx.x;
    const float* wb = w + (size_t)b * L + kc;
    const float* Xb = X + ((size_t)b * L + kc) * DIM;
    float acc0 = 0.f, acc1 = 0.f, acc2 = 0.f;
    for (int kk = 0; kk < 128; ++kk) {
        float wgt = wb[kk];
        if (wgt == 0.f) continue;          // masked keys: exact zero, uniform branch
        const float* row = Xb + (size_t)kk * DIM;
        acc0 += wgt * row[tid];
        acc1 += wgt * row[tid + 256];
        if (tid < 128) acc2 += wgt * row[tid + 512];
    }
    atomicAdd(&pooled[(size_t)b * DIM + tid],       acc0);
    atomicAdd(&pooled[(size_t)b * DIM + tid + 256], acc1);
    if (tid < 128) atomicAdd(&pooled[(size_t)b * DIM + tid + 512], acc2);
}

// ---------------------------------------------------------------------------
// Kernel 4: out[r][o] = pooled[r][:] @ Wv[:,o] + bv[o]   (r = dir*64 + b)
// Valid because sum_k w[b][k] == 1 exactly in exact math -> bias passes through.
// ---------------------------------------------------------------------------
__global__ __launch_bounds__(256)
void outproj_kernel(const float* __restrict__ pooled, const float* __restrict__ Wv,
                    const float* __restrict__ bv, float* __restrict__ out)
{
    const int r = blockIdx.x;                       // 0..127
    const int o = blockIdx.y * 256 + threadIdx.x;   // 0..1023
    const float* p = pooled + (size_t)r * DIM;
    float a0 = bv[o], a1 = 0.f, a2 = 0.f, a3 = 0.f;
    for (int d = 0; d < DIM; d += 4) {
        a0 = fmaf(p[d+0], Wv[(size_t)(d+0)*OUTER + o], a0);
        a1 = fmaf(p[d+1], Wv[(size_t)(d+1)*OUTER + o], a1);
        a2 = fmaf(p[d+2], Wv[(size_t)(d+2)*OUTER + o], a2);
        a3 = fmaf(p[d+3], Wv[(size_t)(d+3)*OUTER + o], a3);
    }
    out[(size_t)r * OUTER + o] = (a0+a1)+(a2+a3);
}

// ---------------------------------------------------------------------------
extern "C" void kernel_launch(void* const* d_in, const int* in_sizes, int n_in,
                              void* d_out, int out_size, void* d_ws, size_t ws_size,
                              hipStream_t stream)
{
    (void)in_sizes; (void)n_in; (void)out_size;
    const float* a_pad = (const float*)d_in[0];
    const float* b_pad = (const float*)d_in[1];
    const int*   len_a = (const int*)d_in[2];
    const int*   len_b = (const int*)d_in[3];
    const float* Wq    = (const float*)d_in[4];
    const float* bq    = (const float*)d_in[5];
    const float* Wk    = (const float*)d_in[6];
    const float* bk    = (const float*)d_in[7];
    const float* Wv    = (const float*)d_in[8];
    const float* bv    = (const float*)d_in[9];
    float* out = (float*)d_out;

    char* ws = (char*)d_ws;
    size_t off = 0;
    auto alloc = [&](size_t bytes) -> float* {
        float* p = (float*)(ws + off);
        off += (bytes + 255) & ~(size_t)255;
        return p;
    };

    const size_t QK = (size_t)BATCH * L * INNER;            // 16.78 M floats
    float* qa = alloc(QK * 4);
    float* ka = alloc(QK * 4);
    float* qb = alloc(QK * 4);
    float* kb = alloc(QK * 4);
    float* l2     = alloc((size_t)2 * BATCH * L * 4);       // row sums, both dirs
    float* w2     = alloc((size_t)2 * BATCH * L * 4);       // averaged attn cols
    float* pooled = alloc((size_t)2 * BATCH * DIM * 4);
    float* E = (float*)(ws + off);
    size_t eAvail = (ws_size > off) ? (ws_size - off) : 0;
    int gb = (int)(eAvail / ((size_t)L * L * 4));           // batches of E that fit
    if (gb < 1) gb = 1;
    if (gb > BATCH) gb = BATCH;

    // 4 QK projections (Wv projection algebraically eliminated)
    dim3 pgrid(512, 4);
    proj_kernel<<<pgrid, 256, 0, stream>>>(a_pad, Wq, bq, qa);
    proj_kernel<<<pgrid, 256, 0, stream>>>(a_pad, Wk, bk, ka);
    proj_kernel<<<pgrid, 256, 0, stream>>>(b_pad, Wq, bq, qb);
    proj_kernel<<<pgrid, 256, 0, stream>>>(b_pad, Wk, bk, kb);

    hipMemsetAsync(l2,     0, (size_t)2 * BATCH * L * 4,   stream);
    hipMemsetAsync(pooled, 0, (size_t)2 * BATCH * DIM * 4, stream);

    for (int dir = 0; dir < 2; ++dir) {
        const float* Q   = (dir == 0) ? qa : qb;
        const float* Km  = (dir == 0) ? kb : ka;
        const int* lenq  = (dir == 0) ? len_a : len_b;
        const int* lenk  = (dir == 0) ? len_b : len_a;
        float* lsum = l2 + (size_t)dir * BATCH * L;
        float* wv   = w2 + (size_t)dir * BATCH * L;
        for (int b0 = 0; b0 < BATCH; b0 += gb) {
            int g = (gb < BATCH - b0) ? gb : (BATCH - b0);
            scores_kernel<<<dim3(8, 16, g), 256, 0, stream>>>(Q, Km, lenk, E, lsum, b0);
            colsum_kernel<<<dim3(4, g),     256, 0, stream>>>(E, lsum, lenq, wv, b0);
        }
    }

    pool_kernel<<<dim3(8, BATCH), 256, 0, stream>>>(w2,                    b_pad, pooled);
    pool_kernel<<<dim3(8, BATCH), 256, 0, stream>>>(w2 + (size_t)BATCH*L,  a_pad, pooled + (size_t)BATCH*DIM);
    outproj_kernel<<<dim3(128, 4), 256, 0, stream>>>(pooled, Wv, bv, out);
}

// Round 2
// 965.763 us; speedup vs baseline: 2.7654x; 2.7654x over previous
//
#include <hip/hip_runtime.h>
#include <hip/hip_bf16.h>
#include <math.h>

#define BATCH 64
#define L 1024
#define DIM 640
#define INNER 256
#define OUTER 1024
#define QKW 512   // fused Q|K projection width

typedef __attribute__((ext_vector_type(8))) short bf16x8;
typedef __attribute__((ext_vector_type(4))) float f32x4;

__device__ __forceinline__ float bf2f(unsigned short u) {
    union { unsigned int i; float f; } v; v.i = ((unsigned int)u) << 16; return v.f;
}
__device__ __forceinline__ unsigned short f2bf(float f) {
    __hip_bfloat16 h = __float2bfloat16(f);
    return *reinterpret_cast<unsigned short*>(&h);
}
__device__ __forceinline__ void gload_lds16(const void* g, void* l) {
    __builtin_amdgcn_global_load_lds(
        (const __attribute__((address_space(1))) void*)g,
        (__attribute__((address_space(3))) void*)l, 16, 0, 0);
}

// ---------------------------------------------------------------------------
// f32 -> bf16 bulk convert (vectorized, grid-stride)
// ---------------------------------------------------------------------------
__global__ __launch_bounds__(256)
void cvt_bf16_kernel(const float* __restrict__ src, unsigned short* __restrict__ dst, int n4)
{
    int i = blockIdx.x * 256 + threadIdx.x;
    const int stride = gridDim.x * 256;
    for (; i < n4; i += stride) {
        float4 v = ((const float4*)src)[i];
        ushort4 o;
        o.x = f2bf(v.x); o.y = f2bf(v.y); o.z = f2bf(v.z); o.w = f2bf(v.w);
        ((ushort4*)dst)[i] = o;
    }
}

// ---------------------------------------------------------------------------
// Wt[512][640] bf16 = concat(Wq^T, Wk^T)
// ---------------------------------------------------------------------------
__global__ __launch_bounds__(256)
void wt_kernel(const float* __restrict__ Wq, const float* __restrict__ Wk,
               unsigned short* __restrict__ Wt)
{
    int idx = blockIdx.x * 256 + threadIdx.x;
    if (idx >= QKW * DIM) return;
    int n = idx / DIM, k = idx - n * DIM;
    float v = (n < INNER) ? Wq[(size_t)k * INNER + n]
                          : Wk[(size_t)k * INNER + (n - INNER)];
    Wt[idx] = f2bf(v);
}

// ---------------------------------------------------------------------------
// Fused Q|K projection: Y[M][512] = X[M][640] @ Wt^T + (bq|bk), bf16 MFMA.
// 128x128 tile, BK=32, 4 waves (2x2), 16x16x32 MFMA, global_load_lds staging.
// ---------------------------------------------------------------------------
__global__ __launch_bounds__(256)
void projqk_kernel(const unsigned short* __restrict__ X,
                   const unsigned short* __restrict__ Wt,
                   const float* __restrict__ bq, const float* __restrict__ bk,
                   unsigned short* __restrict__ Y)
{
    __shared__ unsigned short As[128 * 32];
    __shared__ unsigned short Bs[128 * 32];
    const int tid = threadIdx.x;
    const int w = tid >> 6, l = tid & 63;
    const int bm = blockIdx.x * 128, bn = blockIdx.y * 128;
    const int wr = w >> 1, wc = w & 1;

    const unsigned short* Ag = X  + (size_t)(bm + w*16 + (l>>2)) * DIM + (l&3)*8;
    const unsigned short* Bg = Wt + (size_t)(bn + w*16 + (l>>2)) * DIM + (l&3)*8;
    unsigned short* Al0 = As + w*512;
    unsigned short* Al1 = As + 2048 + w*512;
    unsigned short* Bl0 = Bs + w*512;
    unsigned short* Bl1 = Bs + 2048 + w*512;

    f32x4 acc[4][4] = {};

    for (int k0 = 0; k0 < DIM; k0 += 32) {
        gload_lds16(Ag + k0,                  Al0);
        gload_lds16(Ag + (size_t)64*DIM + k0, Al1);
        gload_lds16(Bg + k0,                  Bl0);
        gload_lds16(Bg + (size_t)64*DIM + k0, Bl1);
        __syncthreads();
        bf16x8 af[4], bfr[4];
        #pragma unroll
        for (int m = 0; m < 4; ++m)
            af[m] = *(const bf16x8*)&As[(wr*64 + m*16 + (l&15))*32 + (l>>4)*8];
        #pragma unroll
        for (int n = 0; n < 4; ++n)
            bfr[n] = *(const bf16x8*)&Bs[(wc*64 + n*16 + (l&15))*32 + (l>>4)*8];
        #pragma unroll
        for (int m = 0; m < 4; ++m)
            #pragma unroll
            for (int n = 0; n < 4; ++n)
                acc[m][n] = __builtin_amdgcn_mfma_f32_16x16x32_bf16(af[m], bfr[n], acc[m][n], 0, 0, 0);
        __syncthreads();
    }

    #pragma unroll
    for (int m = 0; m < 4; ++m)
        #pragma unroll
        for (int n = 0; n < 4; ++n) {
            const int col = bn + wc*64 + n*16 + (l&15);
            const float bias = (col < INNER) ? bq[col] : bk[col - INNER];
            #pragma unroll
            for (int j = 0; j < 4; ++j) {
                const int row = bm + wr*64 + m*16 + (l>>4)*4 + j;
                Y[(size_t)row * QKW + col] = f2bf(acc[m][n][j] + bias);
            }
        }
}

// ---------------------------------------------------------------------------
// Scores: S = Q@K^T / 16, masked exp -> E (bf16), row sums -> lsum (atomic).
// Q rows from QKq (cols 0..255); K rows from QKk (cols 256..511).
// ---------------------------------------------------------------------------
__global__ __launch_bounds__(256)
void scores_kernel(const unsigned short* __restrict__ QKq,
                   const unsigned short* __restrict__ QKk,
                   const int* __restrict__ len_k,
                   unsigned short* __restrict__ E,
                   float* __restrict__ lsum, int b0)
{
    __shared__ unsigned short As[128 * 32];
    __shared__ unsigned short Bs[128 * 32];
    const int tid = threadIdx.x;
    const int w = tid >> 6, l = tid & 63;
    const int bz = blockIdx.z, b = b0 + bz;
    const int bm = blockIdx.x * 128, bn = blockIdx.y * 128;
    const int wr = w >> 1, wc = w & 1;

    const unsigned short* Qg = QKq + ((size_t)b * L + bm + w*16 + (l>>2)) * QKW + (l&3)*8;
    const unsigned short* Kg = QKk + ((size_t)b * L + bn + w*16 + (l>>2)) * QKW + INNER + (l&3)*8;
    unsigned short* Al0 = As + w*512;
    unsigned short* Al1 = As + 2048 + w*512;
    unsigned short* Bl0 = Bs + w*512;
    unsigned short* Bl1 = Bs + 2048 + w*512;

    f32x4 acc[4][4] = {};

    for (int k0 = 0; k0 < INNER; k0 += 32) {
        gload_lds16(Qg + k0,                  Al0);
        gload_lds16(Qg + (size_t)64*QKW + k0, Al1);
        gload_lds16(Kg + k0,                  Bl0);
        gload_lds16(Kg + (size_t)64*QKW + k0, Bl1);
        __syncthreads();
        bf16x8 af[4], bfr[4];
        #pragma unroll
        for (int m = 0; m < 4; ++m)
            af[m] = *(const bf16x8*)&As[(wr*64 + m*16 + (l&15))*32 + (l>>4)*8];
        #pragma unroll
        for (int n = 0; n < 4; ++n)
            bfr[n] = *(const bf16x8*)&Bs[(wc*64 + n*16 + (l&15))*32 + (l>>4)*8];
        #pragma unroll
        for (int m = 0; m < 4; ++m)
            #pragma unroll
            for (int n = 0; n < 4; ++n)
                acc[m][n] = __builtin_amdgcn_mfma_f32_16x16x32_bf16(af[m], bfr[n], acc[m][n], 0, 0, 0);
        __syncthreads();
    }

    const int lenk = len_k[b];
    const float scale = 0.0625f;  // 1/sqrt(256)
    float rs[4][4];
    #pragma unroll
    for (int m = 0; m < 4; ++m)
        #pragma unroll
        for (int j = 0; j < 4; ++j) rs[m][j] = 0.f;

    #pragma unroll
    for (int m = 0; m < 4; ++m)
        #pragma unroll
        for (int n = 0; n < 4; ++n) {
            const int col = bn + wc*64 + n*16 + (l&15);
            const bool valid = col < lenk;
            #pragma unroll
            for (int j = 0; j < 4; ++j) {
                const float e = valid ? __expf(acc[m][n][j] * scale) : 0.f;
                rs[m][j] += e;
                const int row = bm + wr*64 + m*16 + (l>>4)*4 + j;
                E[((size_t)bz * L + row) * L + col] = f2bf(e);
            }
        }

    #pragma unroll
    for (int m = 0; m < 4; ++m)
        #pragma unroll
        for (int j = 0; j < 4; ++j) {
            float v = rs[m][j];
            v += __shfl_xor(v, 1); v += __shfl_xor(v, 2);
            v += __shfl_xor(v, 4); v += __shfl_xor(v, 8);
            if ((l & 15) == 0) {
                const int row = bm + wr*64 + m*16 + (l>>4)*4 + j;
                atomicAdd(&lsum[(size_t)b * L + row], v);
            }
        }
}

// ---------------------------------------------------------------------------
// w[b][k] = (1/len_q) * sum_{q<len_q} E[q][k] / lsum[q]
// ---------------------------------------------------------------------------
__global__ __launch_bounds__(256)
void colsum_kernel(const unsigned short* __restrict__ E, const float* __restrict__ lsum,
                   const int* __restrict__ len_q, float* __restrict__ w, int b0)
{
    const int bz = blockIdx.y, b = b0 + bz;
    const int qc = blockIdx.x * 128;
    const int lq = len_q[b];
    if (qc >= lq) return;
    const int qe = (qc + 128 < lq) ? qc + 128 : lq;
    const int k4 = threadIdx.x * 4;
    const unsigned short* Eb = E + (size_t)bz * L * L + k4;
    const float* lb = lsum + (size_t)b * L;
    const float inv_lq = 1.0f / (float)lq;
    float a0 = 0.f, a1 = 0.f, a2 = 0.f, a3 = 0.f;
    for (int q = qc; q < qe; ++q) {
        ushort4 ev = *(const ushort4*)(Eb + (size_t)q * L);
        float r = inv_lq / lb[q];
        a0 += bf2f(ev.x) * r; a1 += bf2f(ev.y) * r;
        a2 += bf2f(ev.z) * r; a3 += bf2f(ev.w) * r;
    }
    float* wb = w + (size_t)b * L + k4;
    atomicAdd(wb + 0, a0); atomicAdd(wb + 1, a1);
    atomicAdd(wb + 2, a2); atomicAdd(wb + 3, a3);
}

// ---------------------------------------------------------------------------
// pooled[b][d] = sum_k w[b][k] * X[b][k][d]   (f32 exact V path)
// ---------------------------------------------------------------------------
__global__ __launch_bounds__(256)
void pool_kernel(const float* __restrict__ w, const float* __restrict__ X,
                 float* __restrict__ pooled)
{
    const int b   = blockIdx.y;
    const int kc  = blockIdx.x * 128;
    const int tid = threadIdx.x;
    const float* wb = w + (size_t)b * L + kc;
    const float* Xb = X + ((size_t)b * L + kc) * DIM;
    float acc0 = 0.f, acc1 = 0.f, acc2 = 0.f;
    for (int kk = 0; kk < 128; ++kk) {
        float wgt = wb[kk];
        if (wgt == 0.f) continue;
        const float* row = Xb + (size_t)kk * DIM;
        acc0 += wgt * row[tid];
        acc1 += wgt * row[tid + 256];
        if (tid < 128) acc2 += wgt * row[tid + 512];
    }
    atomicAdd(&pooled[(size_t)b * DIM + tid],       acc0);
    atomicAdd(&pooled[(size_t)b * DIM + tid + 256], acc1);
    if (tid < 128) atomicAdd(&pooled[(size_t)b * DIM + tid + 512], acc2);
}

// ---------------------------------------------------------------------------
// out[r][o] = pooled[r][:] @ Wv[:,o] + bv[o]
// ---------------------------------------------------------------------------
__global__ __launch_bounds__(256)
void outproj_kernel(const float* __restrict__ pooled, const float* __restrict__ Wv,
                    const float* __restrict__ bv, float* __restrict__ out)
{
    const int r = blockIdx.x;
    const int o = blockIdx.y * 256 + threadIdx.x;
    const float* p = pooled + (size_t)r * DIM;
    float a0 = bv[o], a1 = 0.f, a2 = 0.f, a3 = 0.f;
    for (int d = 0; d < DIM; d += 4) {
        a0 = fmaf(p[d+0], Wv[(size_t)(d+0)*OUTER + o], a0);
        a1 = fmaf(p[d+1], Wv[(size_t)(d+1)*OUTER + o], a1);
        a2 = fmaf(p[d+2], Wv[(size_t)(d+2)*OUTER + o], a2);
        a3 = fmaf(p[d+3], Wv[(size_t)(d+3)*OUTER + o], a3);
    }
    out[(size_t)r * OUTER + o] = (a0+a1)+(a2+a3);
}

// ---------------------------------------------------------------------------
extern "C" void kernel_launch(void* const* d_in, const int* in_sizes, int n_in,
                              void* d_out, int out_size, void* d_ws, size_t ws_size,
                              hipStream_t stream)
{
    (void)in_sizes; (void)n_in; (void)out_size;
    const float* a_pad = (const float*)d_in[0];
    const float* b_pad = (const float*)d_in[1];
    const int*   len_a = (const int*)d_in[2];
    const int*   len_b = (const int*)d_in[3];
    const float* Wq    = (const float*)d_in[4];
    const float* bq    = (const float*)d_in[5];
    const float* Wk    = (const float*)d_in[6];
    const float* bk    = (const float*)d_in[7];
    const float* Wv    = (const float*)d_in[8];
    const float* bv    = (const float*)d_in[9];
    float* out = (float*)d_out;

    char* ws = (char*)d_ws;
    size_t off = 0;
    auto alloc = [&](size_t bytes) -> void* {
        void* p = (void*)(ws + off);
        off += (bytes + 255) & ~(size_t)255;
        return p;
    };

    const size_t XE = (size_t)BATCH * L * DIM;
    const size_t QE = (size_t)BATCH * L * QKW;
    unsigned short* Xa  = (unsigned short*)alloc(XE * 2);
    unsigned short* Xb  = (unsigned short*)alloc(XE * 2);
    unsigned short* Wt  = (unsigned short*)alloc((size_t)QKW * DIM * 2);
    unsigned short* QKa = (unsigned short*)alloc(QE * 2);
    unsigned short* QKb = (unsigned short*)alloc(QE * 2);
    float* l2     = (float*)alloc((size_t)2 * BATCH * L * 4);
    float* w2     = (float*)alloc((size_t)2 * BATCH * L * 4);
    float* pooled = (float*)alloc((size_t)2 * BATCH * DIM * 4);
    unsigned short* E = (unsigned short*)(ws + off);
    size_t eAvail = (ws_size > off) ? (ws_size - off) : 0;
    int gb = (int)(eAvail / ((size_t)L * L * 2));
    if (gb < 1) gb = 1;
    if (gb > BATCH) gb = BATCH;

    cvt_bf16_kernel<<<2048, 256, 0, stream>>>(a_pad, Xa, (int)(XE / 4));
    cvt_bf16_kernel<<<2048, 256, 0, stream>>>(b_pad, Xb, (int)(XE / 4));
    wt_kernel<<<(QKW * DIM + 255) / 256, 256, 0, stream>>>(Wq, Wk, Wt);

    projqk_kernel<<<dim3(512, 4), 256, 0, stream>>>(Xa, Wt, bq, bk, QKa);
    projqk_kernel<<<dim3(512, 4), 256, 0, stream>>>(Xb, Wt, bq, bk, QKb);

    hipMemsetAsync(l2,     0, (size_t)2 * BATCH * L * 4,   stream);
    hipMemsetAsync(w2,     0, (size_t)2 * BATCH * L * 4,   stream);
    hipMemsetAsync(pooled, 0, (size_t)2 * BATCH * DIM * 4, stream);

    for (int dir = 0; dir < 2; ++dir) {
        const unsigned short* QKq = (dir == 0) ? QKa : QKb;
        const unsigned short* QKk = (dir == 0) ? QKb : QKa;
        const int* lenq = (dir == 0) ? len_a : len_b;
        const int* lenk = (dir == 0) ? len_b : len_a;
        float* lsum = l2 + (size_t)dir * BATCH * L;
        float* wv   = w2 + (size_t)dir * BATCH * L;
        for (int b0 = 0; b0 < BATCH; b0 += gb) {
            int g = (gb < BATCH - b0) ? gb : (BATCH - b0);
            scores_kernel<<<dim3(8, 8, g), 256, 0, stream>>>(QKq, QKk, lenk, E, lsum, b0);
            colsum_kernel<<<dim3(8, g), 256, 0, stream>>>(E, lsum, lenq, wv, b0);
        }
    }

    pool_kernel<<<dim3(8, BATCH), 256, 0, stream>>>(w2,                   b_pad, pooled);
    pool_kernel<<<dim3(8, BATCH), 256, 0, stream>>>(w2 + (size_t)BATCH*L, a_pad, pooled + (size_t)BATCH*DIM);
    outproj_kernel<<<dim3(128, 4), 256, 0, stream>>>(pooled, Wv, bv, out);
}

// Round 4
// 787.264 us; speedup vs baseline: 3.3924x; 1.2267x over previous
//
#include <hip/hip_runtime.h>
#include <hip/hip_bf16.h>
#include <math.h>

#define BATCH 64
#define L 1024
#define DIM 640
#define INNER 256
#define OUTER 1024
#define QKW 512   // fused Q|K projection width

typedef __attribute__((ext_vector_type(8))) short bf16x8;
typedef __attribute__((ext_vector_type(4))) float f32x4;

__device__ __forceinline__ float bf2f(unsigned short u) {
    union { unsigned int i; float f; } v; v.i = ((unsigned int)u) << 16; return v.f;
}
__device__ __forceinline__ unsigned short f2bf(float f) {
    __hip_bfloat16 h = __float2bfloat16(f);
    return *reinterpret_cast<unsigned short*>(&h);
}
__device__ __forceinline__ void gload_lds16(const void* g, void* l) {
    __builtin_amdgcn_global_load_lds(
        (const __attribute__((address_space(1))) void*)g,
        (__attribute__((address_space(3))) void*)l, 16, 0, 0);
}

// ---------------------------------------------------------------------------
// f32 -> bf16 convert, batch-aware: skip rows >= ceil128(len[b]) (never read).
// grid (640, BATCH); block covers 256 float4 = 1024 elems of batch b.
// ---------------------------------------------------------------------------
__global__ __launch_bounds__(256)
void cvt_bf16_kernel(const float* __restrict__ src, unsigned short* __restrict__ dst,
                     const int* __restrict__ len)
{
    const int bx = blockIdx.x, b = blockIdx.y;
    const int R = (len[b] + 127) & ~127;          // needed rows (ceil128)
    if (bx * 8 >= R * 5) return;                  // block start row >= R
    const size_t i = (size_t)b * (L * DIM / 4) + bx * 256 + threadIdx.x;
    float4 v = ((const float4*)src)[i];
    ushort4 o;
    o.x = f2bf(v.x); o.y = f2bf(v.y); o.z = f2bf(v.z); o.w = f2bf(v.w);
    ((ushort4*)dst)[i] = o;
}

// ---------------------------------------------------------------------------
// Wt[512][640] bf16 = concat(Wq^T, Wk^T)
// ---------------------------------------------------------------------------
__global__ __launch_bounds__(256)
void wt_kernel(const float* __restrict__ Wq, const float* __restrict__ Wk,
               unsigned short* __restrict__ Wt)
{
    int idx = blockIdx.x * 256 + threadIdx.x;
    if (idx >= QKW * DIM) return;
    int n = idx / DIM, k = idx - n * DIM;
    float v = (n < INNER) ? Wq[(size_t)k * INNER + n]
                          : Wk[(size_t)k * INNER + (n - INNER)];
    Wt[idx] = f2bf(v);
}

// ---------------------------------------------------------------------------
// Fused Q|K projection: Y[M][512] = X[M][640] @ Wt^T + (bq|bk), bf16 MFMA.
// 1D grid 2048 blocks, bijective XCD-chunked swizzle, n-fast within chunk
// (4 consecutive work-items share one A m-tile -> A read once from HBM).
// Skips m-tiles beyond ceil128(len[batch]) -- those Q/K rows are never read.
// ---------------------------------------------------------------------------
__global__ __launch_bounds__(256)
void projqk_kernel(const unsigned short* __restrict__ X,
                   const unsigned short* __restrict__ Wt,
                   const float* __restrict__ bq, const float* __restrict__ bk,
                   const int* __restrict__ len,
                   unsigned short* __restrict__ Y)
{
    __shared__ unsigned short As[128 * 32];
    __shared__ unsigned short Bs[128 * 32];
    const int bid = blockIdx.x;                 // 2048 = 8 XCD * 256
    const int xcd = bid & 7, idx = bid >> 3;
    const int widx = xcd * 256 + idx;
    const int nt = widx & 3, mt = widx >> 2;    // mt 0..511, n-fast
    const int batch = mt >> 3, mloc = mt & 7;
    if (mloc * 128 >= len[batch]) return;       // rows never read downstream

    const int tid = threadIdx.x;
    const int w = tid >> 6, l = tid & 63;
    const int bm = mt * 128, bn = nt * 128;
    const int wr = w >> 1, wc = w & 1;

    const unsigned short* Ag = X  + (size_t)(bm + w*16 + (l>>2)) * DIM + (l&3)*8;
    const unsigned short* Bg = Wt + (size_t)(bn + w*16 + (l>>2)) * DIM + (l&3)*8;
    unsigned short* Al0 = As + w*512;
    unsigned short* Al1 = As + 2048 + w*512;
    unsigned short* Bl0 = Bs + w*512;
    unsigned short* Bl1 = Bs + 2048 + w*512;

    f32x4 acc[4][4] = {};

    for (int k0 = 0; k0 < DIM; k0 += 32) {
        gload_lds16(Ag + k0,                  Al0);
        gload_lds16(Ag + (size_t)64*DIM + k0, Al1);
        gload_lds16(Bg + k0,                  Bl0);
        gload_lds16(Bg + (size_t)64*DIM + k0, Bl1);
        __syncthreads();
        bf16x8 af[4], bfr[4];
        #pragma unroll
        for (int m = 0; m < 4; ++m)
            af[m] = *(const bf16x8*)&As[(wr*64 + m*16 + (l&15))*32 + (l>>4)*8];
        #pragma unroll
        for (int n = 0; n < 4; ++n)
            bfr[n] = *(const bf16x8*)&Bs[(wc*64 + n*16 + (l&15))*32 + (l>>4)*8];
        #pragma unroll
        for (int m = 0; m < 4; ++m)
            #pragma unroll
            for (int n = 0; n < 4; ++n)
                acc[m][n] = __builtin_amdgcn_mfma_f32_16x16x32_bf16(af[m], bfr[n], acc[m][n], 0, 0, 0);
        __syncthreads();
    }

    #pragma unroll
    for (int m = 0; m < 4; ++m)
        #pragma unroll
        for (int n = 0; n < 4; ++n) {
            const int col = bn + wc*64 + n*16 + (l&15);
            const float bias = (col < INNER) ? bq[col] : bk[col - INNER];
            #pragma unroll
            for (int j = 0; j < 4; ++j) {
                const int row = bm + wr*64 + m*16 + (l>>4)*4 + j;
                Y[(size_t)row * QKW + col] = f2bf(acc[m][n][j] + bias);
            }
        }
}

// ---------------------------------------------------------------------------
// Scores: S = Q@K^T / 16, masked exp -> E (bf16), row sums -> lsum (atomic).
// Q rows from QKq (cols 0..255); K rows from QKk (cols 256..511).
// Early-exit tiles fully outside (len_q, len_k): identical numerics
// (skipped tiles contributed exactly 0 to lsum and are never read from E).
// ---------------------------------------------------------------------------
__global__ __launch_bounds__(256)
void scores_kernel(const unsigned short* __restrict__ QKq,
                   const unsigned short* __restrict__ QKk,
                   const int* __restrict__ len_q,
                   const int* __restrict__ len_k,
                   unsigned short* __restrict__ E,
                   float* __restrict__ lsum, int b0)
{
    __shared__ unsigned short As[128 * 32];
    __shared__ unsigned short Bs[128 * 32];
    const int bz = blockIdx.z, b = b0 + bz;
    const int bm = blockIdx.x * 128, bn = blockIdx.y * 128;
    const int lq = len_q[b], lenk = len_k[b];
    if (bm >= lq || bn >= lenk) return;          // contributes nothing

    const int tid = threadIdx.x;
    const int w = tid >> 6, l = tid & 63;
    const int wr = w >> 1, wc = w & 1;

    const unsigned short* Qg = QKq + ((size_t)b * L + bm + w*16 + (l>>2)) * QKW + (l&3)*8;
    const unsigned short* Kg = QKk + ((size_t)b * L + bn + w*16 + (l>>2)) * QKW + INNER + (l&3)*8;
    unsigned short* Al0 = As + w*512;
    unsigned short* Al1 = As + 2048 + w*512;
    unsigned short* Bl0 = Bs + w*512;
    unsigned short* Bl1 = Bs + 2048 + w*512;

    f32x4 acc[4][4] = {};

    for (int k0 = 0; k0 < INNER; k0 += 32) {
        gload_lds16(Qg + k0,                  Al0);
        gload_lds16(Qg + (size_t)64*QKW + k0, Al1);
        gload_lds16(Kg + k0,                  Bl0);
        gload_lds16(Kg + (size_t)64*QKW + k0, Bl1);
        __syncthreads();
        bf16x8 af[4], bfr[4];
        #pragma unroll
        for (int m = 0; m < 4; ++m)
            af[m] = *(const bf16x8*)&As[(wr*64 + m*16 + (l&15))*32 + (l>>4)*8];
        #pragma unroll
        for (int n = 0; n < 4; ++n)
            bfr[n] = *(const bf16x8*)&Bs[(wc*64 + n*16 + (l&15))*32 + (l>>4)*8];
        #pragma unroll
        for (int m = 0; m < 4; ++m)
            #pragma unroll
            for (int n = 0; n < 4; ++n)
                acc[m][n] = __builtin_amdgcn_mfma_f32_16x16x32_bf16(af[m], bfr[n], acc[m][n], 0, 0, 0);
        __syncthreads();
    }

    const float scale = 0.0625f;  // 1/sqrt(256)
    float rs[4][4];
    #pragma unroll
    for (int m = 0; m < 4; ++m)
        #pragma unroll
        for (int j = 0; j < 4; ++j) rs[m][j] = 0.f;

    #pragma unroll
    for (int m = 0; m < 4; ++m)
        #pragma unroll
        for (int n = 0; n < 4; ++n) {
            const int col = bn + wc*64 + n*16 + (l&15);
            const bool valid = col < lenk;
            #pragma unroll
            for (int j = 0; j < 4; ++j) {
                const float e = valid ? __expf(acc[m][n][j] * scale) : 0.f;
                rs[m][j] += e;
                const int row = bm + wr*64 + m*16 + (l>>4)*4 + j;
                E[((size_t)bz * L + row) * L + col] = f2bf(e);
            }
        }

    #pragma unroll
    for (int m = 0; m < 4; ++m)
        #pragma unroll
        for (int j = 0; j < 4; ++j) {
            float v = rs[m][j];
            v += __shfl_xor(v, 1); v += __shfl_xor(v, 2);
            v += __shfl_xor(v, 4); v += __shfl_xor(v, 8);
            if ((l & 15) == 0) {
                const int row = bm + wr*64 + m*16 + (l>>4)*4 + j;
                atomicAdd(&lsum[(size_t)b * L + row], v);
            }
        }
}

// ---------------------------------------------------------------------------
// w[b][k] = (1/len_q) * sum_{q<len_q} E[q][k] / lsum[q]
// Threads with k >= len_k exit (w stays 0 from memset; E there may be unwritten).
// ---------------------------------------------------------------------------
__global__ __launch_bounds__(256)
void colsum_kernel(const unsigned short* __restrict__ E, const float* __restrict__ lsum,
                   const int* __restrict__ len_q, const int* __restrict__ len_k,
                   float* __restrict__ w, int b0)
{
    const int bz = blockIdx.y, b = b0 + bz;
    const int qc = blockIdx.x * 128;
    const int lq = len_q[b];
    if (qc >= lq) return;
    const int k4 = threadIdx.x * 4;
    if (k4 >= len_k[b]) return;                  // never written / all-zero weight
    const int qe = (qc + 128 < lq) ? qc + 128 : lq;
    const unsigned short* Eb = E + (size_t)bz * L * L + k4;
    const float* lb = lsum + (size_t)b * L;
    const float inv_lq = 1.0f / (float)lq;
    float a0 = 0.f, a1 = 0.f, a2 = 0.f, a3 = 0.f;
    for (int q = qc; q < qe; ++q) {
        ushort4 ev = *(const ushort4*)(Eb + (size_t)q * L);
        float r = inv_lq / lb[q];
        a0 += bf2f(ev.x) * r; a1 += bf2f(ev.y) * r;
        a2 += bf2f(ev.z) * r; a3 += bf2f(ev.w) * r;
    }
    float* wb = w + (size_t)b * L + k4;
    atomicAdd(wb + 0, a0); atomicAdd(wb + 1, a1);
    atomicAdd(wb + 2, a2); atomicAdd(wb + 3, a3);
}

// ---------------------------------------------------------------------------
// pooled[b][d] = sum_k w[b][k] * X[b][k][d]   (f32 exact V path)
// ---------------------------------------------------------------------------
__global__ __launch_bounds__(256)
void pool_kernel(const float* __restrict__ w, const float* __restrict__ X,
                 float* __restrict__ pooled)
{
    const int b   = blockIdx.y;
    const int kc  = blockIdx.x * 128;
    const int tid = threadIdx.x;
    const float* wb = w + (size_t)b * L + kc;
    const float* Xb = X + ((size_t)b * L + kc) * DIM;
    float acc0 = 0.f, acc1 = 0.f, acc2 = 0.f;
    for (int kk = 0; kk < 128; ++kk) {
        float wgt = wb[kk];
        if (wgt == 0.f) continue;   // masked keys: exact zero, uniform branch
        const float* row = Xb + (size_t)kk * DIM;
        acc0 += wgt * row[tid];
        acc1 += wgt * row[tid + 256];
        if (tid < 128) acc2 += wgt * row[tid + 512];
    }
    atomicAdd(&pooled[(size_t)b * DIM + tid],       acc0);
    atomicAdd(&pooled[(size_t)b * DIM + tid + 256], acc1);
    if (tid < 128) atomicAdd(&pooled[(size_t)b * DIM + tid + 512], acc2);
}

// ---------------------------------------------------------------------------
// out[r][o] = pooled[r][:] @ Wv[:,o] + bv[o]
// ---------------------------------------------------------------------------
__global__ __launch_bounds__(256)
void outproj_kernel(const float* __restrict__ pooled, const float* __restrict__ Wv,
                    const float* __restrict__ bv, float* __restrict__ out)
{
    const int r = blockIdx.x;
    const int o = blockIdx.y * 256 + threadIdx.x;
    const float* p = pooled + (size_t)r * DIM;
    float a0 = bv[o], a1 = 0.f, a2 = 0.f, a3 = 0.f;
    for (int d = 0; d < DIM; d += 4) {
        a0 = fmaf(p[d+0], Wv[(size_t)(d+0)*OUTER + o], a0);
        a1 = fmaf(p[d+1], Wv[(size_t)(d+1)*OUTER + o], a1);
        a2 = fmaf(p[d+2], Wv[(size_t)(d+2)*OUTER + o], a2);
        a3 = fmaf(p[d+3], Wv[(size_t)(d+3)*OUTER + o], a3);
    }
    out[(size_t)r * OUTER + o] = (a0+a1)+(a2+a3);
}

// ---------------------------------------------------------------------------
extern "C" void kernel_launch(void* const* d_in, const int* in_sizes, int n_in,
                              void* d_out, int out_size, void* d_ws, size_t ws_size,
                              hipStream_t stream)
{
    (void)in_sizes; (void)n_in; (void)out_size;
    const float* a_pad = (const float*)d_in[0];
    const float* b_pad = (const float*)d_in[1];
    const int*   len_a = (const int*)d_in[2];
    const int*   len_b = (const int*)d_in[3];
    const float* Wq    = (const float*)d_in[4];
    const float* bq    = (const float*)d_in[5];
    const float* Wk    = (const float*)d_in[6];
    const float* bk    = (const float*)d_in[7];
    const float* Wv    = (const float*)d_in[8];
    const float* bv    = (const float*)d_in[9];
    float* out = (float*)d_out;

    char* ws = (char*)d_ws;
    size_t off = 0;
    auto alloc = [&](size_t bytes) -> void* {
        void* p = (void*)(ws + off);
        off += (bytes + 255) & ~(size_t)255;
        return p;
    };

    const size_t XE = (size_t)BATCH * L * DIM;
    const size_t QE = (size_t)BATCH * L * QKW;
    unsigned short* Xa  = (unsigned short*)alloc(XE * 2);
    unsigned short* Xb  = (unsigned short*)alloc(XE * 2);
    unsigned short* Wt  = (unsigned short*)alloc((size_t)QKW * DIM * 2);
    unsigned short* QKa = (unsigned short*)alloc(QE * 2);
    unsigned short* QKb = (unsigned short*)alloc(QE * 2);
    float* l2     = (float*)alloc((size_t)2 * BATCH * L * 4);
    float* w2     = (float*)alloc((size_t)2 * BATCH * L * 4);
    float* pooled = (float*)alloc((size_t)2 * BATCH * DIM * 4);
    unsigned short* E = (unsigned short*)(ws + off);
    size_t eAvail = (ws_size > off) ? (ws_size - off) : 0;
    int gb = (int)(eAvail / ((size_t)L * L * 2));
    if (gb < 1) gb = 1;
    if (gb > BATCH) gb = BATCH;

    cvt_bf16_kernel<<<dim3(640, BATCH), 256, 0, stream>>>(a_pad, Xa, len_a);
    cvt_bf16_kernel<<<dim3(640, BATCH), 256, 0, stream>>>(b_pad, Xb, len_b);
    wt_kernel<<<(QKW * DIM + 255) / 256, 256, 0, stream>>>(Wq, Wk, Wt);

    projqk_kernel<<<2048, 256, 0, stream>>>(Xa, Wt, bq, bk, len_a, QKa);
    projqk_kernel<<<2048, 256, 0, stream>>>(Xb, Wt, bq, bk, len_b, QKb);

    hipMemsetAsync(l2,     0, (size_t)2 * BATCH * L * 4,   stream);
    hipMemsetAsync(w2,     0, (size_t)2 * BATCH * L * 4,   stream);
    hipMemsetAsync(pooled, 0, (size_t)2 * BATCH * DIM * 4, stream);

    for (int dir = 0; dir < 2; ++dir) {
        const unsigned short* QKq = (dir == 0) ? QKa : QKb;
        const unsigned short* QKk = (dir == 0) ? QKb : QKa;
        const int* lenq = (dir == 0) ? len_a : len_b;
        const int* lenk = (dir == 0) ? len_b : len_a;
        float* lsum = l2 + (size_t)dir * BATCH * L;
        float* wv   = w2 + (size_t)dir * BATCH * L;
        for (int b0 = 0; b0 < BATCH; b0 += gb) {
            int g = (gb < BATCH - b0) ? gb : (BATCH - b0);
            scores_kernel<<<dim3(8, 8, g), 256, 0, stream>>>(QKq, QKk, lenq, lenk, E, lsum, b0);
            colsum_kernel<<<dim3(8, g), 256, 0, stream>>>(E, lsum, lenq, lenk, wv, b0);
        }
    }

    pool_kernel<<<dim3(8, BATCH), 256, 0, stream>>>(w2,                   b_pad, pooled);
    pool_kernel<<<dim3(8, BATCH), 256, 0, stream>>>(w2 + (size_t)BATCH*L, a_pad, pooled + (size_t)BATCH*DIM);
    outproj_kernel<<<dim3(128, 4), 256, 0, stream>>>(pooled, Wv, bv, out);
}